// Round 1
// baseline (302.041 us; speedup 1.0000x reference)
//
#include <hip/hip_runtime.h>
#include <hip/hip_bf16.h>

typedef float f4 __attribute__((ext_vector_type(4)));
typedef short s8 __attribute__((ext_vector_type(8)));

__device__ __forceinline__ short f2bf(float f) {
  union { float f; unsigned u; } v; v.f = f;
  unsigned r = v.u + 0x7fffu + ((v.u >> 16) & 1u);
  return (short)(r >> 16);
}

// ---------------------------------------------------------------------------
// MFMA GEMM: C[M x S] = A[M x Kd] @ B[Kd x S] per batch (blockIdx.z).
// MODE 0: K1  A=wkv_bf16 (shared), B=x f32 -> K/V bf16 split + sumsq(K rows)
// MODE 1: K2  A=wq_bf16  (shared), B=query f32 -> Q bf16 + sumsq
// MODE 2: K6  A=M_b bf16 (per batch), B=V bf16 -> out f32
// MODE 3: K5  A=wproj_bf16 (shared), B=BD bf16 (per batch) -> M_b bf16
// Tile 128x128, BK=64, 4 waves (2x2), each wave 64x64 via 4x4 16x16x32 mfma.
// LDS rows padded to 72 bf16 (144 B) -> all b128 LDS ops conflict-free.
// ---------------------------------------------------------------------------
template<int MODE>
__global__ __launch_bounds__(256)
void gemm_k(const short* __restrict__ A_, const float* __restrict__ B32_,
            const short* __restrict__ B16_, short* __restrict__ O16a,
            short* __restrict__ O16b, float* __restrict__ O32,
            float* __restrict__ ss) {
  constexpr int Kd = (MODE == 1) ? 192 : 384;
  constexpr int Sd = (MODE == 3) ? 384 : 4096;
  constexpr bool INF32 = (MODE <= 1);
  constexpr bool SUMSQ = (MODE <= 1);
  constexpr long ABST = (MODE == 2) ? 384L * 384 : 0;
  constexpr long BBST = (MODE == 0) ? 384L * 4096 : (MODE == 1) ? 192L * 4096
                        : (MODE == 2) ? 384L * 4096 : 384L * 384;
  constexpr int LDK = 72;

  __shared__ short As[128 * LDK];
  __shared__ short Bs[128 * LDK];

  const int tid = threadIdx.x;
  const int bz = blockIdx.z;
  const int m0 = blockIdx.x * 128;
  const int s0 = blockIdx.y * 128;

  const short* Ag = A_ + (long)bz * ABST;
  const float* Bg32 = INF32 ? (B32_ + (long)bz * BBST) : nullptr;
  const short* Bg16 = INF32 ? nullptr : (B16_ + (long)bz * BBST);

  const int lane = tid & 63;
  const int wid = tid >> 6;
  const int l15 = lane & 15, lhi = lane >> 4;
  const int wm = (wid >> 1) * 64, wn = (wid & 1) * 64;

  f4 acc[4][4];
#pragma unroll
  for (int i = 0; i < 4; ++i)
#pragma unroll
    for (int j = 0; j < 4; ++j) acc[i][j] = (f4){0.f, 0.f, 0.f, 0.f};

#pragma unroll 1
  for (int kt = 0; kt < Kd / 64; ++kt) {
    const int k0 = kt * 64;
    __syncthreads();
    // stage A tile [128 rows x 64 k] bf16, b128 chunks
#pragma unroll
    for (int it = 0; it < 4; ++it) {
      int idx = it * 256 + tid;
      int row = idx >> 3, kc = (idx & 7) * 8;
      s8 v = *(const s8*)(Ag + (long)(m0 + row) * Kd + k0 + kc);
      *(s8*)(&As[row * LDK + kc]) = v;
    }
    // stage B tile transposed: Bs[s][k], gather 8 k per thread, one b128 write
#pragma unroll
    for (int it = 0; it < 4; ++it) {
      int idx = it * 256 + tid;
      int sl = idx & 127, kg = (idx >> 7) * 8;
      s8 hv;
      if (INF32) {
#pragma unroll
        for (int j = 0; j < 8; ++j)
          hv[j] = f2bf(Bg32[(long)(k0 + kg + j) * Sd + s0 + sl]);
      } else {
#pragma unroll
        for (int j = 0; j < 8; ++j)
          hv[j] = Bg16[(long)(k0 + kg + j) * Sd + s0 + sl];
      }
      *(s8*)(&Bs[sl * LDK + kg]) = hv;
    }
    __syncthreads();
#pragma unroll
    for (int kk = 0; kk < 64; kk += 32) {
      s8 af[4], bfr[4];
#pragma unroll
      for (int i = 0; i < 4; ++i) {
        af[i] = *(const s8*)(&As[(wm + i * 16 + l15) * LDK + kk + lhi * 8]);
        bfr[i] = *(const s8*)(&Bs[(wn + i * 16 + l15) * LDK + kk + lhi * 8]);
      }
#pragma unroll
      for (int mi = 0; mi < 4; ++mi)
#pragma unroll
        for (int ni = 0; ni < 4; ++ni)
          acc[mi][ni] = __builtin_amdgcn_mfma_f32_16x16x32_bf16(
              af[mi], bfr[ni], acc[mi][ni], 0, 0, 0);
    }
  }

  // epilogue: C/D layout col = lane&15, row = (lane>>4)*4 + r  [m89-verified]
#pragma unroll
  for (int mi = 0; mi < 4; ++mi) {
#pragma unroll
    for (int r = 0; r < 4; ++r) {
      const int rowl = wm + mi * 16 + lhi * 4 + r;
      const int grow = m0 + rowl;
      if (SUMSQ) {
        float t = 0.f;
#pragma unroll
        for (int ni = 0; ni < 4; ++ni) { float v = acc[mi][ni][r]; t += v * v; }
        t += __shfl_xor(t, 1);
        t += __shfl_xor(t, 2);
        t += __shfl_xor(t, 4);
        t += __shfl_xor(t, 8);
        bool doss = (MODE == 1) || (grow < 384);
        if (doss && l15 == 0) atomicAdd(&ss[bz * 384 + grow], t);
      }
#pragma unroll
      for (int ni = 0; ni < 4; ++ni) {
        const int col = s0 + wn + ni * 16 + l15;
        float v = acc[mi][ni][r];
        if (MODE == 0) {
          if (grow < 384)
            O16a[((long)bz * 384 + grow) * 4096 + col] = f2bf(v);
          else
            O16b[((long)bz * 384 + (grow - 384)) * 4096 + col] = f2bf(v);
        } else if (MODE == 1) {
          O16a[((long)bz * 384 + grow) * 4096 + col] = f2bf(v);
        } else if (MODE == 2) {
          O32[((long)bz * 384 + grow) * 4096 + col] = v;
        } else {
          O16a[((long)bz * 384 + grow) * 384 + col] = f2bf(v);
        }
      }
    }
  }
}

// ---------------------------------------------------------------------------
// K3: partial raw-dot S[c][d] = sum_s Q[c,s]*K[d,s] per (b,h,zslice).
// Spatial dim is contiguous => both mfma operands are direct b128 global loads
// (each byte read exactly once; no LDS staging needed).
// ---------------------------------------------------------------------------
__global__ __launch_bounds__(256)
void attn_k(const short* __restrict__ Kb, const short* __restrict__ Qb,
            float* __restrict__ Spart) {
  const int b = blockIdx.x, h = blockIdx.y, z = blockIdx.z;
  const int tid = threadIdx.x;
  const int lane = tid & 63, wid = tid >> 6;
  const int l15 = lane & 15, lhi = lane >> 4;
  const long base = ((long)b * 384 + h * 48) * 4096;

  f4 acc[3][3];
#pragma unroll
  for (int i = 0; i < 3; ++i)
#pragma unroll
    for (int j = 0; j < 3; ++j) acc[i][j] = (f4){0.f, 0.f, 0.f, 0.f};

  const int sb = z * 1024 + wid * 256;
  for (int st = 0; st < 8; ++st) {
    const int s0 = sb + st * 32 + lhi * 8;
    s8 qa[3], ka[3];
#pragma unroll
    for (int i = 0; i < 3; ++i) {
      qa[i] = *(const s8*)(Qb + base + (long)(i * 16 + l15) * 4096 + s0);
      ka[i] = *(const s8*)(Kb + base + (long)(i * 16 + l15) * 4096 + s0);
    }
#pragma unroll
    for (int mi = 0; mi < 3; ++mi)
#pragma unroll
      for (int ni = 0; ni < 3; ++ni)
        acc[mi][ni] = __builtin_amdgcn_mfma_f32_16x16x32_bf16(
            qa[mi], ka[ni], acc[mi][ni], 0, 0, 0);
  }
  __shared__ float Sl[2304];
  for (int i = tid; i < 2304; i += 256) Sl[i] = 0.f;
  __syncthreads();
#pragma unroll
  for (int mi = 0; mi < 3; ++mi)
#pragma unroll
    for (int ni = 0; ni < 3; ++ni)
#pragma unroll
      for (int r = 0; r < 4; ++r) {
        int c = mi * 16 + lhi * 4 + r;
        int d = ni * 16 + l15;
        atomicAdd(&Sl[c * 48 + d], acc[mi][ni][r]);
      }
  __syncthreads();
  float* op = Spart + (((long)z * 16 + b) * 8 + h) * 2304;
  for (int i = tid; i < 2304; i += 256) op[i] = Sl[i];
}

// ---------------------------------------------------------------------------
// K4: reduce z-partials, logits = S * rnq[c] * rnk[d] * temp[h], row-softmax,
// write probs (bf16) into block-diagonal BD[b][384][384] (rest stays zero).
// ---------------------------------------------------------------------------
__global__ __launch_bounds__(256)
void softmax_k(const float* __restrict__ Spart, const float* __restrict__ ssq,
               const float* __restrict__ ssk, const float* __restrict__ temp,
               short* __restrict__ BD) {
  const int b = blockIdx.x, h = blockIdx.y;
  const int tid = threadIdx.x;
  __shared__ float L[2304];
  __shared__ float rq[48], rk[48], mrow[48], irow[48];
  if (tid < 48) {
    rq[tid] = 1.f / fmaxf(sqrtf(ssq[b * 384 + h * 48 + tid]), 1e-12f);
    rk[tid] = 1.f / fmaxf(sqrtf(ssk[b * 384 + h * 48 + tid]), 1e-12f);
  }
  __syncthreads();
  const float tp = temp[h];
  for (int i = tid; i < 2304; i += 256) {
    float v = 0.f;
#pragma unroll
    for (int z = 0; z < 4; ++z)
      v += Spart[(((long)z * 16 + b) * 8 + h) * 2304 + i];
    int c = i / 48, d = i % 48;
    L[i] = v * rq[c] * rk[d] * tp;
  }
  __syncthreads();
  if (tid < 48) {
    float m = -1e30f;
    for (int d = 0; d < 48; ++d) m = fmaxf(m, L[tid * 48 + d]);
    float s = 0.f;
    for (int d = 0; d < 48; ++d) s += __expf(L[tid * 48 + d] - m);
    mrow[tid] = m;
    irow[tid] = 1.f / s;
  }
  __syncthreads();
  for (int i = tid; i < 2304; i += 256) {
    int c = i / 48, d = i % 48;
    float p = __expf(L[i] - mrow[c]) * irow[c];
    BD[((long)b * 384 + h * 48 + c) * 384 + h * 48 + d] = f2bf(p);
  }
}

// K0: cast the three weight matrices to bf16 once per launch.
__global__ void prep_k(const float* __restrict__ wkv, const float* __restrict__ wq,
                       const float* __restrict__ wp, short* __restrict__ wkvb,
                       short* __restrict__ wqb, short* __restrict__ wpb) {
  int i = blockIdx.x * 256 + threadIdx.x;
  if (i < 294912) wkvb[i] = f2bf(wkv[i]);
  else if (i < 368640) wqb[i - 294912] = f2bf(wq[i - 294912]);
  else if (i < 516096) wpb[i - 368640] = f2bf(wp[i - 368640]);
}

extern "C" void kernel_launch(void* const* d_in, const int* in_sizes, int n_in,
                              void* d_out, int out_size, void* d_ws, size_t ws_size,
                              hipStream_t stream) {
  const float* x = (const float*)d_in[0];
  const float* query = (const float*)d_in[1];
  const float* w_kv = (const float*)d_in[2];
  const float* w_q = (const float*)d_in[3];
  const float* w_proj = (const float*)d_in[4];
  const float* temp = (const float*)d_in[5];

  // workspace carve (~65.6 MB), all 16B-aligned offsets
  char* w = (char*)d_ws;
  short* Vbuf = (short*)w;  w += 50331648;          // V bf16 [16][384][4096]
  float* ssq = (float*)w;   w += 24576;             // sumsq q rows [16*384]
  float* ssk = (float*)w;   w += 24576;             // sumsq k rows [16*384]
  float* Spart = (float*)w; w += 4718592;           // [4][16][8][48*48] f32
  short* BD = (short*)w;    w += 4718592;           // blockdiag probs bf16
  short* Mbuf = (short*)w;  w += 4718592;           // M_b = Wproj@BD bf16
  short* wkvb = (short*)w;  w += 589824;
  short* wqb = (short*)w;   w += 147456;
  short* wpb = (short*)w;   w += 294912;

  // stash K and Q (bf16) inside d_out; both fully consumed by attn_k before
  // the final GEMM overwrites d_out with the f32 result (stream-ordered).
  short* Kbuf = (short*)d_out;
  short* Qbuf = (short*)d_out + 25165824;
  float* out = (float*)d_out;

  hipMemsetAsync(ssq, 0, 49152, stream);       // ssq+ssk contiguous
  hipMemsetAsync(BD, 0, 4718592, stream);

  prep_k<<<2016, 256, 0, stream>>>(w_kv, w_q, w_proj, wkvb, wqb, wpb);
  // K/V = w_kv @ x  (+ sumsq of K rows)
  gemm_k<0><<<dim3(6, 32, 16), 256, 0, stream>>>(wkvb, x, nullptr, Kbuf, Vbuf,
                                                 nullptr, ssk);
  // Q = w_q @ query (+ sumsq)
  gemm_k<1><<<dim3(3, 32, 16), 256, 0, stream>>>(wqb, query, nullptr, Qbuf,
                                                 nullptr, nullptr, ssq);
  // raw channel dots, 4-way spatial split
  attn_k<<<dim3(16, 8, 4), 256, 0, stream>>>(Kbuf, Qbuf, Spart);
  // normalize + temperature + softmax -> block-diagonal probs
  softmax_k<<<dim3(16, 8), 256, 0, stream>>>(Spart, ssq, ssk, temp, BD);
  // M_b = Wproj @ BD_b   (folds attn@V and proj into one big GEMM)
  gemm_k<3><<<dim3(3, 3, 16), 256, 0, stream>>>(wpb, nullptr, BD, Mbuf,
                                                nullptr, nullptr, nullptr);
  // out = M_b @ V_b
  gemm_k<2><<<dim3(3, 32, 16), 256, 0, stream>>>(Mbuf, nullptr, Vbuf, nullptr,
                                                 nullptr, out, nullptr);
}

// Round 2
// 239.114 us; speedup vs baseline: 1.2632x; 1.2632x over previous
//
#include <hip/hip_runtime.h>
#include <hip/hip_bf16.h>

typedef float f4 __attribute__((ext_vector_type(4)));
typedef short s8 __attribute__((ext_vector_type(8)));
typedef short s4 __attribute__((ext_vector_type(4)));

__device__ __forceinline__ short f2bf(float f) {
  union { float f; unsigned u; } v; v.f = f;
  unsigned r = v.u + 0x7fffu + ((v.u >> 16) & 1u);
  return (short)(r >> 16);
}

// async global->LDS, 16B per lane, LDS dest = wave-uniform base + lane*16
__device__ __forceinline__ void gl16(const short* g, short* l) {
  __builtin_amdgcn_global_load_lds(
      (const __attribute__((address_space(1))) unsigned*)g,
      (__attribute__((address_space(3))) unsigned*)l, 16, 0, 0);
}

// ---------------------------------------------------------------------------
// Unified MFMA GEMM, all operands bf16 row-major with CONTIGUOUS contraction
// (B^T layout, m97 structure): C[m][n] = sum_k A[m][k] * B[n][k].
// MODE 0: K = wk @ xT^T      A=wkb[384x384]      B=xT[b][4096x384]  -> K bf16 + ssk
// MODE 1: Q = wq @ qT^T      A=wqb[384x192]      B=qT[b][4096x192]  -> Q bf16 + ssq
// MODE 2: out = N_b @ xT^T   A=Nb[b][384x384]    B=xT[b]            -> f32 out
// MODE 3: T' = WvT @ BD^T    A=WvT[384x384]      B=BD[b][384x384]   -> T' bf16
// MODE 4: N  = wp @ T'^T     A=wpb[384x384]      B=T'[b][384x384]   -> N bf16
// Tile 128x128, BK=64, 4 waves (2x2), 4x4 16x16x32 mfma per wave.
// Staging via global_load_lds dwordx4 (linear LDS [128][64]).
// ---------------------------------------------------------------------------
template<int MODE>
__global__ __launch_bounds__(256)
void gemm2(const short* __restrict__ A_, const short* __restrict__ B_,
           short* __restrict__ O16, float* __restrict__ O32,
           float* __restrict__ ss) {
  constexpr int Kd = (MODE == 1) ? 192 : 384;
  constexpr long ASTR = (MODE == 2) ? 384L * 384 : 0;
  constexpr long BSTR = (MODE == 0 || MODE == 2) ? 4096L * 384
                        : (MODE == 1) ? 4096L * 192 : 384L * 384;
  constexpr int OST = (MODE >= 3) ? 384 : 4096;
  constexpr bool SUMSQ = (MODE <= 1);

  __shared__ __align__(16) short As[128 * 64];
  __shared__ __align__(16) short Bs[128 * 64];

  const int tid = threadIdx.x;
  int m0, n0, bz;
  if (MODE <= 2) {
    // XCD-chunk swizzle: blocks on one XCD get a contiguous work range so the
    // 3 m-blocks sharing a B tile land on the same XCD L2. nwg=1536, 1536%8==0.
    int flat = blockIdx.x + 3 * (blockIdx.y + 32 * blockIdx.z);
    int w = (flat & 7) * 192 + (flat >> 3);
    m0 = (w % 3) * 128;
    n0 = ((w / 3) & 31) * 128;
    bz = w / 96;
  } else {
    m0 = blockIdx.x * 128; n0 = blockIdx.y * 128; bz = blockIdx.z;
  }

  const short* Ag = A_ + (long)bz * ASTR;
  const short* Bg = B_ + (long)bz * BSTR;

  const int lane = tid & 63;
  const int wid = tid >> 6;
  const int l15 = lane & 15, lhi = lane >> 4;
  const int wm = (wid >> 1) * 64, wn = (wid & 1) * 64;
  const int srow = tid >> 3;          // staging row within 32-row chunk
  const int skc = (tid & 7) * 8;      // staging k offset (elements)

  f4 acc[4][4];
#pragma unroll
  for (int i = 0; i < 4; ++i)
#pragma unroll
    for (int j = 0; j < 4; ++j) acc[i][j] = (f4){0.f, 0.f, 0.f, 0.f};

  for (int kt = 0; kt < Kd / 64; ++kt) {
    const int k0 = kt * 64;
    __syncthreads();
#pragma unroll
    for (int it = 0; it < 4; ++it) {
      const int r = it * 32 + srow;
      gl16(Ag + (long)(m0 + r) * Kd + k0 + skc, &As[(it * 256 + tid) * 8]);
      gl16(Bg + (long)(n0 + r) * Kd + k0 + skc, &Bs[(it * 256 + tid) * 8]);
    }
    __syncthreads();
#pragma unroll
    for (int kk = 0; kk < 64; kk += 32) {
      s8 af[4], bf[4];
#pragma unroll
      for (int i = 0; i < 4; ++i) {
        af[i] = *(const s8*)(&As[(wm + i * 16 + l15) * 64 + kk + lhi * 8]);
        bf[i] = *(const s8*)(&Bs[(wn + i * 16 + l15) * 64 + kk + lhi * 8]);
      }
#pragma unroll
      for (int mi = 0; mi < 4; ++mi)
#pragma unroll
        for (int ni = 0; ni < 4; ++ni)
          acc[mi][ni] = __builtin_amdgcn_mfma_f32_16x16x32_bf16(
              af[mi], bf[ni], acc[mi][ni], 0, 0, 0);
    }
  }

  // epilogue: C/D layout col = lane&15, row = (lane>>4)*4 + r
#pragma unroll
  for (int mi = 0; mi < 4; ++mi) {
#pragma unroll
    for (int r = 0; r < 4; ++r) {
      const int grow = m0 + wm + mi * 16 + lhi * 4 + r;
      if (SUMSQ) {
        float t = 0.f;
#pragma unroll
        for (int ni = 0; ni < 4; ++ni) { float v = acc[mi][ni][r]; t += v * v; }
        t += __shfl_xor(t, 1);
        t += __shfl_xor(t, 2);
        t += __shfl_xor(t, 4);
        t += __shfl_xor(t, 8);
        if (l15 == 0) atomicAdd(&ss[bz * 384 + grow], t);
      }
#pragma unroll
      for (int ni = 0; ni < 4; ++ni) {
        const int col = n0 + wn + ni * 16 + l15;
        const float v = acc[mi][ni][r];
        if (MODE == 2)
          O32[((long)bz * 384 + grow) * 4096 + col] = v;
        else
          O16[((long)bz * 384 + grow) * OST + col] = f2bf(v);
      }
    }
  }
}

// ---------------------------------------------------------------------------
// Transpose+cast: src f32 [16][C][4096] -> dst bf16 [16][4096][C].
// 64x64 tiles through LDS (pad 65 -> conflict-free), coalesced both sides.
// ---------------------------------------------------------------------------
__global__ __launch_bounds__(256)
void trans_k(const float* __restrict__ src, short* __restrict__ dst, int C) {
  __shared__ float Ls[64][65];
  const int tid = threadIdx.x;
  const int c0 = blockIdx.x * 64, s0 = blockIdx.y * 64;
  const long bb = (long)blockIdx.z * C * 4096;
  const int rr = tid >> 4;
  const int cq = (tid & 15) * 4;
#pragma unroll
  for (int it = 0; it < 4; ++it) {
    const int r = it * 16 + rr;
    f4 v = *(const f4*)(src + bb + (long)(c0 + r) * 4096 + s0 + cq);
    Ls[r][cq + 0] = v.x; Ls[r][cq + 1] = v.y;
    Ls[r][cq + 2] = v.z; Ls[r][cq + 3] = v.w;
  }
  __syncthreads();
  const long ob = (long)blockIdx.z * 4096 * C;
#pragma unroll
  for (int it = 0; it < 4; ++it) {
    const int sr = it * 16 + rr;
    s4 o;
#pragma unroll
    for (int j = 0; j < 4; ++j) o[j] = f2bf(Ls[cq + j][sr]);
    *(s4*)(dst + ob + (long)(s0 + sr) * C + c0 + cq) = o;
  }
}

// ---------------------------------------------------------------------------
// K3: partial raw-dot S[c][d] = sum_s Q[c,s]*K[d,s] per (b,h,zslice).
// ---------------------------------------------------------------------------
__global__ __launch_bounds__(256)
void attn_k(const short* __restrict__ Kb, const short* __restrict__ Qb,
            float* __restrict__ Spart) {
  const int b = blockIdx.x, h = blockIdx.y, z = blockIdx.z;
  const int tid = threadIdx.x;
  const int lane = tid & 63, wid = tid >> 6;
  const int l15 = lane & 15, lhi = lane >> 4;
  const long base = ((long)b * 384 + h * 48) * 4096;

  f4 acc[3][3];
#pragma unroll
  for (int i = 0; i < 3; ++i)
#pragma unroll
    for (int j = 0; j < 3; ++j) acc[i][j] = (f4){0.f, 0.f, 0.f, 0.f};

  const int sb = z * 1024 + wid * 256;
  for (int st = 0; st < 8; ++st) {
    const int s0 = sb + st * 32 + lhi * 8;
    s8 qa[3], ka[3];
#pragma unroll
    for (int i = 0; i < 3; ++i) {
      qa[i] = *(const s8*)(Qb + base + (long)(i * 16 + l15) * 4096 + s0);
      ka[i] = *(const s8*)(Kb + base + (long)(i * 16 + l15) * 4096 + s0);
    }
#pragma unroll
    for (int mi = 0; mi < 3; ++mi)
#pragma unroll
      for (int ni = 0; ni < 3; ++ni)
        acc[mi][ni] = __builtin_amdgcn_mfma_f32_16x16x32_bf16(
            qa[mi], ka[ni], acc[mi][ni], 0, 0, 0);
  }
  __shared__ float Sl[2304];
  for (int i = tid; i < 2304; i += 256) Sl[i] = 0.f;
  __syncthreads();
#pragma unroll
  for (int mi = 0; mi < 3; ++mi)
#pragma unroll
    for (int ni = 0; ni < 3; ++ni)
#pragma unroll
      for (int r = 0; r < 4; ++r) {
        int c = mi * 16 + lhi * 4 + r;
        int d = ni * 16 + l15;
        atomicAdd(&Sl[c * 48 + d], acc[mi][ni][r]);
      }
  __syncthreads();
  float* op = Spart + (((long)z * 16 + b) * 8 + h) * 2304;
  for (int i = tid; i < 2304; i += 256) op[i] = Sl[i];
}

// ---------------------------------------------------------------------------
// K4: reduce z-partials, logits = S*rnq*rnk*temp, row-softmax -> BD (bf16).
// ---------------------------------------------------------------------------
__global__ __launch_bounds__(256)
void softmax_k(const float* __restrict__ Spart, const float* __restrict__ ssq,
               const float* __restrict__ ssk, const float* __restrict__ temp,
               short* __restrict__ BD) {
  const int b = blockIdx.x, h = blockIdx.y;
  const int tid = threadIdx.x;
  __shared__ float L[2304];
  __shared__ float rq[48], rk[48], mrow[48], irow[48];
  if (tid < 48) {
    rq[tid] = 1.f / fmaxf(sqrtf(ssq[b * 384 + h * 48 + tid]), 1e-12f);
    rk[tid] = 1.f / fmaxf(sqrtf(ssk[b * 384 + h * 48 + tid]), 1e-12f);
  }
  __syncthreads();
  const float tp = temp[h];
  for (int i = tid; i < 2304; i += 256) {
    float v = 0.f;
#pragma unroll
    for (int z = 0; z < 4; ++z)
      v += Spart[(((long)z * 16 + b) * 8 + h) * 2304 + i];
    int c = i / 48, d = i % 48;
    L[i] = v * rq[c] * rk[d] * tp;
  }
  __syncthreads();
  if (tid < 48) {
    float m = -1e30f;
    for (int d = 0; d < 48; ++d) m = fmaxf(m, L[tid * 48 + d]);
    float s = 0.f;
    for (int d = 0; d < 48; ++d) s += __expf(L[tid * 48 + d] - m);
    mrow[tid] = m;
    irow[tid] = 1.f / s;
  }
  __syncthreads();
  for (int i = tid; i < 2304; i += 256) {
    int c = i / 48, d = i % 48;
    float p = __expf(L[i] - mrow[c]) * irow[c];
    BD[((long)b * 384 + h * 48 + c) * 384 + h * 48 + d] = f2bf(p);
  }
}

// weights: wk (top half of w_kv), WvT (transposed bottom half), wq, wp -> bf16
__global__ void wprep_k(const float* __restrict__ wkv, const float* __restrict__ wq,
                        const float* __restrict__ wp, short* __restrict__ wkb,
                        short* __restrict__ WvT, short* __restrict__ wqb,
                        short* __restrict__ wpb) {
  int i = blockIdx.x * 256 + threadIdx.x;
  if (i < 147456) {
    wkb[i] = f2bf(wkv[i]);
  } else if (i < 294912) {
    int t = i - 147456;
    int j = t / 384, d = t % 384;
    WvT[t] = f2bf(wkv[(384 + d) * 384 + j]);
  } else if (i < 368640) {
    wqb[i - 294912] = f2bf(wq[i - 294912]);
  } else if (i < 516096) {
    wpb[i - 368640] = f2bf(wp[i - 368640]);
  }
}

extern "C" void kernel_launch(void* const* d_in, const int* in_sizes, int n_in,
                              void* d_out, int out_size, void* d_ws, size_t ws_size,
                              hipStream_t stream) {
  const float* x = (const float*)d_in[0];
  const float* query = (const float*)d_in[1];
  const float* w_kv = (const float*)d_in[2];
  const float* w_q = (const float*)d_in[3];
  const float* w_proj = (const float*)d_in[4];
  const float* temp = (const float*)d_in[5];

  // workspace carve (~58 MB)
  char* w = (char*)d_ws;
  short* xT = (short*)w;           // [16][4096][384] bf16
  float* ssq = (float*)(w + 50331648);
  float* ssk = (float*)(w + 50356224);
  float* Spart = (float*)(w + 50380800);   // [4][16][8][2304] f32; later T'
  short* Tp = (short*)(w + 50380800);      // alias: T' bf16 [16][384][384]
  short* BD = (short*)(w + 55099392);      // blockdiag probs bf16; later N
  short* Nb = (short*)(w + 55099392);      // alias: N bf16 [16][384][384]
  short* wkb = (short*)(w + 59817984);
  short* WvT = (short*)(w + 60112896);
  short* wqb = (short*)(w + 60407808);
  short* wpb = (short*)(w + 60555264);

  // d_out staging: qT first (consumed by Q-GEMM), then K overwrites it;
  // Q sits in the upper half; final GEMM overwrites everything with f32 out.
  short* qT = (short*)d_out;                    // [16][4096][192] bf16
  short* Kb = (short*)d_out;                    // [16][384][4096] bf16
  short* Qb = (short*)d_out + 25165824;         // [16][384][4096] bf16
  float* out = (float*)d_out;

  hipMemsetAsync(ssq, 0, 49152, stream);        // ssq+ssk contiguous
  hipMemsetAsync(BD, 0, 4718592, stream);

  wprep_k<<<2016, 256, 0, stream>>>(w_kv, w_q, w_proj, wkb, WvT, wqb, wpb);
  trans_k<<<dim3(6, 64, 16), 256, 0, stream>>>(x, xT, 384);
  trans_k<<<dim3(3, 64, 16), 256, 0, stream>>>(query, qT, 192);
  // Q = wq @ query (reads qT from d_out lower half, writes Q to upper half)
  gemm2<1><<<dim3(3, 32, 16), 256, 0, stream>>>(wqb, qT, Qb, nullptr, ssq);
  // K = wk @ x (overwrites qT region — qT fully consumed above)
  gemm2<0><<<dim3(3, 32, 16), 256, 0, stream>>>(wkb, xT, Kb, nullptr, ssk);
  // raw channel dots, 4-way spatial split
  attn_k<<<dim3(16, 8, 4), 256, 0, stream>>>(Kb, Qb, Spart);
  // normalize + temperature + softmax -> block-diagonal probs
  softmax_k<<<dim3(16, 8), 256, 0, stream>>>(Spart, ssq, ssk, temp, BD);
  // T' = WvT @ BD^T   (T'[j][c] = (BD@Wv)[c][j])
  gemm2<3><<<dim3(3, 3, 16), 256, 0, stream>>>(WvT, BD, Tp, nullptr, nullptr);
  // N = wp @ T'^T     (N_b = W_proj @ BD_b @ W_v)
  gemm2<4><<<dim3(3, 3, 16), 256, 0, stream>>>(wpb, Tp, Nb, nullptr, nullptr);
  // out = N_b @ x_b
  gemm2<2><<<dim3(3, 32, 16), 256, 0, stream>>>(Nb, xT, nullptr, out, nullptr);
}